// Round 3
// baseline (399.328 us; speedup 1.0000x reference)
//
#include <hip/hip_runtime.h>

typedef __attribute__((ext_vector_type(8))) short short8;
typedef __attribute__((ext_vector_type(4))) float floatx4;
typedef unsigned short u16;

// Problem constants (fixed by the reference)
#define KMAXN 32

__device__ __forceinline__ u16 f2b(float f) {
    unsigned u = __builtin_bit_cast(unsigned, f);
    u += 0x7FFFu + ((u >> 16) & 1u);   // RNE (finite values only)
    return (u16)(u >> 16);
}
__device__ __forceinline__ float silu_f(float x) {
    return x / (1.f + __expf(-x));
}

// ---------------------------------------------------------------------------
// Kernel 1: x_b = silu(h @ W_down)   f32 [N,256]x[256,64] -> bf16 [N,64] in ws
// 16 atoms per block, 4 waves; wave w computes output cols [16w,16w+16).
// ---------------------------------------------------------------------------
__global__ __launch_bounds__(256) void k_down(const float* __restrict__ h,
                                              const float* __restrict__ Wd,
                                              u16* __restrict__ xb) {
    const int tid  = threadIdx.x;
    const int wave = tid >> 6;
    const int lane = tid & 63;
    const int m = lane & 15;     // atom within tile (A rows); out col for B/D
    const int q = lane >> 4;     // quad
    const long atom0 = (long)blockIdx.x * 16;

    const float* arow = h + (atom0 + m) * 256 + q * 8;
    floatx4 acc = {0.f, 0.f, 0.f, 0.f};
#pragma unroll
    for (int kk = 0; kk < 8; ++kk) {
        float4 f0 = *reinterpret_cast<const float4*>(arow + kk * 32);
        float4 f1 = *reinterpret_cast<const float4*>(arow + kk * 32 + 4);
        short8 a;
        a[0] = (short)f2b(f0.x); a[1] = (short)f2b(f0.y);
        a[2] = (short)f2b(f0.z); a[3] = (short)f2b(f0.w);
        a[4] = (short)f2b(f1.x); a[5] = (short)f2b(f1.y);
        a[6] = (short)f2b(f1.z); a[7] = (short)f2b(f1.w);
        short8 b;
#pragma unroll
        for (int j = 0; j < 8; ++j) {
            int k = kk * 32 + q * 8 + j;
            b[j] = (short)f2b(Wd[k * 64 + wave * 16 + m]);
        }
        acc = __builtin_amdgcn_mfma_f32_16x16x32_bf16(a, b, acc, 0, 0, 0);
    }
#pragma unroll
    for (int r = 0; r < 4; ++r) {
        int row = q * 4 + r;   // atom within tile
        xb[(atom0 + row) * 64 + wave * 16 + m] = f2b(silu_f(acc[r]));
    }
}

// ---------------------------------------------------------------------------
// Kernel 2: last-write-wins scatter resolution (numpy semantics: highest
// edge id wins for duplicate (dst, k) slots).
// ---------------------------------------------------------------------------
__global__ __launch_bounds__(256) void k_winner(const int* __restrict__ edst,
                                                const int* __restrict__ tni,
                                                int* __restrict__ winner, int E) {
    int e = blockIdx.x * 256 + threadIdx.x;
    if (e < E) {
        atomicMax(&winner[edst[e] * KMAXN + tni[e]], e);
    }
}

// ---------------------------------------------------------------------------
// Kernel 3: fused  einsum('nrk,nkd', rad, x2) -> @W_bilinear*scale -> silu(@W_up)
// Block = 256 threads (4 waves) = 16 atoms. x2 built per-wave in LDS from the
// winner table (never touches HBM).
// ---------------------------------------------------------------------------
#define TL_STRIDE 1032   // 1024 + 8 pad: row byte-stride 2064 -> 2-way bank alias (free)

__global__ __launch_bounds__(256) void k_fused(
        const float* __restrict__ rad,     // [N][16][32] f32
        const u16*   __restrict__ xb,      // [N][64] bf16
        const int*   __restrict__ winner,  // [N*32], -1 = empty
        const int*   __restrict__ esrc,    // edge_index row 0
        const float* __restrict__ Wb,      // [1024][64] f32
        const float* __restrict__ Wu,      // [64][256] f32
        const float* __restrict__ scale_p, // [1] f32
        float* __restrict__ out) {         // [N][256] f32
    __shared__ alignas(16) u16 t_lds[16][TL_STRIDE];  // 33 KB: x_ba2 per atom, r*64+d
    __shared__ alignas(16) u16 c2_lds[16][72];        // 2.3 KB: scaled h_out (bf16)
    __shared__ alignas(16) u16 x2s[4][KMAXN][64];     // 16 KB: per-wave scatter buffer

    const int tid  = threadIdx.x;
    const int wave = tid >> 6;
    const int lane = tid & 63;
    const int m = lane & 15;
    const int q = lane >> 4;
    const long atom0 = (long)blockIdx.x * 16;

    // ---- Phase A: per-wave, 4 atoms: build x2 then einsum via 4 MFMAs ----
    for (int a = 0; a < 4; ++a) {
        const long n = atom0 + wave * 4 + a;

        // Build x2[wave]: lane pair handles one slot; each lane covers
        // 32 u16 (= 64 B = 4x uint4) of the 64-wide xb row.
        {
            int slot = lane >> 1;
            int half = lane & 1;
            int w = winner[n * KMAXN + slot];
            uint4 v0 = {0, 0, 0, 0}, v1 = {0, 0, 0, 0};
            uint4 v2 = {0, 0, 0, 0}, v3 = {0, 0, 0, 0};
            if (w >= 0) {
                int src = esrc[w];
                const uint4* p = reinterpret_cast<const uint4*>(xb + (long)src * 64 + half * 32);
                v0 = p[0]; v1 = p[1]; v2 = p[2]; v3 = p[3];
            }
            uint4* d = reinterpret_cast<uint4*>(&x2s[wave][slot][half * 32]);
            d[0] = v0; d[1] = v1; d[2] = v2; d[3] = v3;
        }
        __syncthreads();

        // A-frag: rad[n] is [16 r][32 k] row-major f32 -> two float4 loads
        const float* rrow = rad + n * 512 + m * 32 + q * 8;
        float4 r0 = *reinterpret_cast<const float4*>(rrow);
        float4 r1 = *reinterpret_cast<const float4*>(rrow + 4);
        short8 ra;
        ra[0] = (short)f2b(r0.x); ra[1] = (short)f2b(r0.y);
        ra[2] = (short)f2b(r0.z); ra[3] = (short)f2b(r0.w);
        ra[4] = (short)f2b(r1.x); ra[5] = (short)f2b(r1.y);
        ra[6] = (short)f2b(r1.z); ra[7] = (short)f2b(r1.w);

        // einsum: D[r][d] = sum_k rad[r][k] * x2[k][d]; 4 col-tiles of 16
#pragma unroll
        for (int c = 0; c < 4; ++c) {
            short8 bx;
#pragma unroll
            for (int j = 0; j < 8; ++j) {
                bx[j] = (short)x2s[wave][q * 8 + j][c * 16 + m];
            }
            floatx4 tz = {0.f, 0.f, 0.f, 0.f};
            tz = __builtin_amdgcn_mfma_f32_16x16x32_bf16(ra, bx, tz, 0, 0, 0);
#pragma unroll
            for (int r = 0; r < 4; ++r) {
                int rbf = q * 4 + r;                        // row of D = rbf index
                t_lds[wave * 4 + a][rbf * 64 + c * 16 + m] = f2b(tz[r]);
            }
        }
        __syncthreads();
    }

    // ---- Phase B: C2[16 atoms][64] = t[16][1024] @ Wb[1024][64], * scale ----
    floatx4 c2 = {0.f, 0.f, 0.f, 0.f};
    for (int kk = 0; kk < 32; ++kk) {
        short8 af = *reinterpret_cast<const short8*>(&t_lds[m][kk * 32 + q * 8]);
        short8 bf;
#pragma unroll
        for (int j = 0; j < 8; ++j) {
            int k = kk * 32 + q * 8 + j;
            bf[j] = (short)f2b(Wb[k * 64 + wave * 16 + m]);
        }
        c2 = __builtin_amdgcn_mfma_f32_16x16x32_bf16(af, bf, c2, 0, 0, 0);
    }
    {
        float sc = scale_p[0];
#pragma unroll
        for (int r = 0; r < 4; ++r) {
            c2_lds[q * 4 + r][wave * 16 + m] = f2b(c2[r] * sc);
        }
    }
    __syncthreads();

    // ---- Phase C: out = silu(C2 @ Wu)  [16,64]x[64,256]; wave w -> cols [64w,64w+64) ----
#pragma unroll
    for (int tt = 0; tt < 4; ++tt) {
        floatx4 acc = {0.f, 0.f, 0.f, 0.f};
#pragma unroll
        for (int ks = 0; ks < 2; ++ks) {
            short8 af = *reinterpret_cast<const short8*>(&c2_lds[m][ks * 32 + q * 8]);
            short8 bf;
#pragma unroll
            for (int j = 0; j < 8; ++j) {
                int k = ks * 32 + q * 8 + j;
                bf[j] = (short)f2b(Wu[k * 256 + wave * 64 + tt * 16 + m]);
            }
            acc = __builtin_amdgcn_mfma_f32_16x16x32_bf16(af, bf, acc, 0, 0, 0);
        }
#pragma unroll
        for (int r = 0; r < 4; ++r) {
            int row = q * 4 + r;   // atom within tile
            out[(atom0 + row) * 256 + wave * 64 + tt * 16 + m] = silu_f(acc[r]);
        }
    }
}

// ---------------------------------------------------------------------------
extern "C" void kernel_launch(void* const* d_in, const int* in_sizes, int n_in,
                              void* d_out, int out_size, void* d_ws, size_t ws_size,
                              hipStream_t stream) {
    const float* h     = (const float*)d_in[0];
    const float* rad   = (const float*)d_in[1];
    const int*   eidx  = (const int*)d_in[2];   // [2][E]
    const int*   tni   = (const int*)d_in[3];   // [E]
    const float* Wd    = (const float*)d_in[4];
    const float* Wb    = (const float*)d_in[5];
    const float* Wu    = (const float*)d_in[6];
    const float* scale = (const float*)d_in[7];
    float* out         = (float*)d_out;

    const int E = in_sizes[3];            // 1,600,000
    const int N = in_sizes[0] / 256;      // 50,000

    // Workspace: xb bf16 [N*64] then winner int32 [N*32]
    u16* xb = (u16*)d_ws;
    size_t xb_bytes = (size_t)N * 64 * sizeof(u16);          // 6.4 MB
    int* winner = (int*)((char*)d_ws + xb_bytes);

    hipMemsetAsync(winner, 0xFF, (size_t)N * KMAXN * sizeof(int), stream);
    k_down<<<N / 16, 256, 0, stream>>>(h, Wd, xb);
    k_winner<<<(E + 255) / 256, 256, 0, stream>>>(eidx + E, tni, winner, E);
    k_fused<<<N / 16, 256, 0, stream>>>(rad, xb, winner, eidx, Wb, Wu, scale, out);
}

// Round 4
// 364.276 us; speedup vs baseline: 1.0962x; 1.0962x over previous
//
#include <hip/hip_runtime.h>

typedef __attribute__((ext_vector_type(8))) short short8;
typedef __attribute__((ext_vector_type(4))) float floatx4;
typedef unsigned short u16;
typedef unsigned long long u64;

#define KMAXN 32

__device__ __forceinline__ u16 f2b(float f) {
    unsigned u = __builtin_bit_cast(unsigned, f);
    u += 0x7FFFu + ((u >> 16) & 1u);   // RNE (finite values only)
    return (u16)(u >> 16);
}
__device__ __forceinline__ float silu_f(float x) {
    return x / (1.f + __expf(-x));
}

// ---------------------------------------------------------------------------
// k_xpose: weights f32 -> bf16, transposed to [n][k] so B-fragments are
// contiguous 16B loads.  WdT[64][256], WbT[64][1024], WuT[256][64].
// 98304 elems = 384 blocks x 256.
// ---------------------------------------------------------------------------
__global__ __launch_bounds__(256) void k_xpose(const float* __restrict__ Wd,
                                               const float* __restrict__ Wb,
                                               const float* __restrict__ Wu,
                                               u16* __restrict__ WdT,
                                               u16* __restrict__ WbT,
                                               u16* __restrict__ WuT) {
    int idx = blockIdx.x * 256 + threadIdx.x;
    if (idx < 16384) {                       // WdT[n][k] = Wd[k*64+n]
        WdT[idx] = f2b(Wd[(idx & 255) * 64 + (idx >> 8)]);
    } else if (idx < 81920) {                // WbT[n][k] = Wb[k*64+n]
        int i = idx - 16384;
        WbT[i] = f2b(Wb[(i & 1023) * 64 + (i >> 10)]);
    } else {                                 // WuT[n][k] = Wu[k*256+n]
        int i = idx - 81920;
        WuT[i] = f2b(Wu[(i & 63) * 256 + (i >> 6)]);
    }
}

// ---------------------------------------------------------------------------
// k_prep: fused down-projection (blocks [0, DOWN)) + winner scatter
// (blocks [DOWN, DOWN+WIN)).  Independent roles, overlapped in one launch.
// ---------------------------------------------------------------------------
__global__ __launch_bounds__(256) void k_prep(const float* __restrict__ h,
                                              const u16*   __restrict__ WdT,  // [64][256] bf16
                                              u16*         __restrict__ xb,
                                              const int*   __restrict__ edst,
                                              const int*   __restrict__ tni,
                                              int*         __restrict__ winner,
                                              int E, int DOWN) {
    const int tid = threadIdx.x;
    if ((int)blockIdx.x >= DOWN) {
        // ---- winner role: last-write-wins via atomicMax on edge id ----
        int e = (blockIdx.x - DOWN) * 256 + tid;
        if (e < E) atomicMax(&winner[edst[e] * KMAXN + tni[e]], e);
        return;
    }
    // ---- down role: xb = silu(h @ Wd) as bf16, 16 atoms/block ----
    const int wave = tid >> 6;
    const int lane = tid & 63;
    const int m = lane & 15;
    const int q = lane >> 4;
    const long atom0 = (long)blockIdx.x * 16;

    const float* arow = h + (atom0 + m) * 256 + q * 8;
    const u16* brow = WdT + (wave * 16 + m) * 256 + q * 8;
    floatx4 acc = {0.f, 0.f, 0.f, 0.f};
#pragma unroll
    for (int kk = 0; kk < 8; ++kk) {
        float4 f0 = *reinterpret_cast<const float4*>(arow + kk * 32);
        float4 f1 = *reinterpret_cast<const float4*>(arow + kk * 32 + 4);
        short8 a;
        a[0] = (short)f2b(f0.x); a[1] = (short)f2b(f0.y);
        a[2] = (short)f2b(f0.z); a[3] = (short)f2b(f0.w);
        a[4] = (short)f2b(f1.x); a[5] = (short)f2b(f1.y);
        a[6] = (short)f2b(f1.z); a[7] = (short)f2b(f1.w);
        short8 b = *reinterpret_cast<const short8*>(brow + kk * 32);
        acc = __builtin_amdgcn_mfma_f32_16x16x32_bf16(a, b, acc, 0, 0, 0);
    }
#pragma unroll
    for (int r = 0; r < 4; ++r) {
        int row = q * 4 + r;
        xb[(atom0 + row) * 64 + wave * 16 + m] = f2b(silu_f(acc[r]));
    }
}

// ---------------------------------------------------------------------------
// k_resolve: winner edge-id -> source-atom id (in place), int4-vectorized.
// Removes the dependent esrc gather from k_fused's critical chain.
// ---------------------------------------------------------------------------
__global__ __launch_bounds__(256) void k_resolve(int* __restrict__ winner,
                                                 const int* __restrict__ esrc,
                                                 int n4) {
    int i = blockIdx.x * 256 + threadIdx.x;
    if (i < n4) {
        int4 w = reinterpret_cast<int4*>(winner)[i];
        w.x = (w.x >= 0) ? esrc[w.x] : -1;
        w.y = (w.y >= 0) ? esrc[w.y] : -1;
        w.z = (w.z >= 0) ? esrc[w.z] : -1;
        w.w = (w.w >= 0) ? esrc[w.w] : -1;
        reinterpret_cast<int4*>(winner)[i] = w;
    }
}

// ---------------------------------------------------------------------------
// k_fused: einsum('nrk,nkd', rad, x2) -> @Wb*scale -> silu(@Wu)
// 256 thr = 4 waves = 16 atoms.  Phase A is barrier-free (wave-private LDS).
// ---------------------------------------------------------------------------
#define TL_STRIDE 1032   // t row: 1024 + 8 pad (2064B, 16B-aligned)
#define X2_PAD    68     // x2 row: 64 + 4 pad (136B): q-groups 4-way -> 2-way (free)

__global__ __launch_bounds__(256) void k_fused(
        const float* __restrict__ rad,     // [N][16][32] f32
        const u16*   __restrict__ xb,      // [N][64] bf16
        const int*   __restrict__ winner,  // [N*32] resolved src ids, -1 = empty
        const u16*   __restrict__ WbT,     // [64][1024] bf16
        const u16*   __restrict__ WuT,     // [256][64] bf16
        const float* __restrict__ scale_p, // [1]
        float* __restrict__ out) {         // [N][256] f32
    __shared__ alignas(16) u16 t_lds[16][TL_STRIDE];   // 33.0 KB
    __shared__ alignas(16) u16 c2_lds[16][72];         //  2.3 KB
    __shared__ alignas(16) u16 x2s[4][KMAXN][X2_PAD];  // 17.4 KB  (52.7 KB total -> 3 blk/CU)

    const int tid  = threadIdx.x;
    const int wave = tid >> 6;
    const int lane = tid & 63;
    const int m = lane & 15;
    const int q = lane >> 4;
    const long atom0 = (long)blockIdx.x * 16;
    const long nbase = atom0 + wave * 4;

    // ---- Phase A: 4 atoms per wave, barrier-free ----
    const int slot = lane >> 1;
    const int half = lane & 1;

    // 1) all 4 winner ids (independent random loads, one latency)
    int src[4];
#pragma unroll
    for (int a = 0; a < 4; ++a) src[a] = winner[(nbase + a) * KMAXN + slot];

    // 2) all 4 rad A-fragments (streaming)
    short8 ra[4];
#pragma unroll
    for (int a = 0; a < 4; ++a) {
        const float* rrow = rad + (nbase + a) * 512 + m * 32 + q * 8;
        float4 r0 = *reinterpret_cast<const float4*>(rrow);
        float4 r1 = *reinterpret_cast<const float4*>(rrow + 4);
        ra[a][0] = (short)f2b(r0.x); ra[a][1] = (short)f2b(r0.y);
        ra[a][2] = (short)f2b(r0.z); ra[a][3] = (short)f2b(r0.w);
        ra[a][4] = (short)f2b(r1.x); ra[a][5] = (short)f2b(r1.y);
        ra[a][6] = (short)f2b(r1.z); ra[a][7] = (short)f2b(r1.w);
    }

    // 3) all 4 gathers (each lane: 32 u16 = 64B = 4 x uint4)
    uint4 g[4][4];
#pragma unroll
    for (int a = 0; a < 4; ++a) {
        if (src[a] >= 0) {
            const uint4* p = reinterpret_cast<const uint4*>(xb + (long)src[a] * 64 + half * 32);
            g[a][0] = p[0]; g[a][1] = p[1]; g[a][2] = p[2]; g[a][3] = p[3];
        } else {
            uint4 z = {0, 0, 0, 0};
            g[a][0] = z; g[a][1] = z; g[a][2] = z; g[a][3] = z;
        }
    }

#pragma unroll
    for (int a = 0; a < 4; ++a) {
        // write this atom's x2 into the wave-private buffer (8 x b64, 8B-aligned)
        u64* d = reinterpret_cast<u64*>(&x2s[wave][slot][half * 32]);
        const u64* s = reinterpret_cast<const u64*>(&g[a][0]);
#pragma unroll
        for (int i = 0; i < 8; ++i) d[i] = s[i];
        asm volatile("s_waitcnt lgkmcnt(0)" ::: "memory");  // drain wave's LDS writes

#pragma unroll
        for (int c = 0; c < 4; ++c) {
            short8 bx;
#pragma unroll
            for (int j = 0; j < 8; ++j) {
                bx[j] = (short)x2s[wave][q * 8 + j][c * 16 + m];
            }
            floatx4 tz = {0.f, 0.f, 0.f, 0.f};
            tz = __builtin_amdgcn_mfma_f32_16x16x32_bf16(ra[a], bx, tz, 0, 0, 0);
#pragma unroll
            for (int r = 0; r < 4; ++r) {
                t_lds[wave * 4 + a][(q * 4 + r) * 64 + c * 16 + m] = f2b(tz[r]);
            }
        }
        asm volatile("" ::: "memory");  // keep reads of a before writes of a+1
    }
    __syncthreads();   // t_lds crosses waves below

    // ---- Phase B: C2[16][64] = t[16][1024] @ Wb, * scale ----
    floatx4 c2 = {0.f, 0.f, 0.f, 0.f};
    const u16* wbrow = WbT + (wave * 16 + m) * 1024 + q * 8;
#pragma unroll 4
    for (int kk = 0; kk < 32; ++kk) {
        short8 af = *reinterpret_cast<const short8*>(&t_lds[m][kk * 32 + q * 8]);
        short8 bf = *reinterpret_cast<const short8*>(wbrow + kk * 32);
        c2 = __builtin_amdgcn_mfma_f32_16x16x32_bf16(af, bf, c2, 0, 0, 0);
    }
    {
        float sc = scale_p[0];
#pragma unroll
        for (int r = 0; r < 4; ++r) {
            c2_lds[q * 4 + r][wave * 16 + m] = f2b(c2[r] * sc);
        }
    }
    __syncthreads();

    // ---- Phase C: out = silu(C2 @ Wu); wave w -> cols [64w, 64w+64) ----
#pragma unroll
    for (int tt = 0; tt < 4; ++tt) {
        floatx4 acc = {0.f, 0.f, 0.f, 0.f};
        const u16* wurow = WuT + (wave * 64 + tt * 16 + m) * 64 + q * 8;
#pragma unroll
        for (int ks = 0; ks < 2; ++ks) {
            short8 af = *reinterpret_cast<const short8*>(&c2_lds[m][ks * 32 + q * 8]);
            short8 bf = *reinterpret_cast<const short8*>(wurow + ks * 32);
            acc = __builtin_amdgcn_mfma_f32_16x16x32_bf16(af, bf, acc, 0, 0, 0);
        }
#pragma unroll
        for (int r = 0; r < 4; ++r) {
            out[(atom0 + q * 4 + r) * 256 + wave * 64 + tt * 16 + m] = silu_f(acc[r]);
        }
    }
}

// ---------------------------------------------------------------------------
extern "C" void kernel_launch(void* const* d_in, const int* in_sizes, int n_in,
                              void* d_out, int out_size, void* d_ws, size_t ws_size,
                              hipStream_t stream) {
    const float* h     = (const float*)d_in[0];
    const float* rad   = (const float*)d_in[1];
    const int*   eidx  = (const int*)d_in[2];   // [2][E]: row0 = src, row1 = dst
    const int*   tni   = (const int*)d_in[3];
    const float* Wd    = (const float*)d_in[4];
    const float* Wb    = (const float*)d_in[5];
    const float* Wu    = (const float*)d_in[6];
    const float* scale = (const float*)d_in[7];
    float* out         = (float*)d_out;

    const int E = in_sizes[3];            // 1,600,000
    const int N = in_sizes[0] / 256;      // 50,000

    // Workspace: xb bf16 [N*64] | winner int32 [N*32] | WdT | WbT | WuT
    u16* xb = (u16*)d_ws;
    size_t off = (size_t)N * 64 * sizeof(u16);                 // 6.4 MB
    int* winner = (int*)((char*)d_ws + off);
    off += (size_t)N * KMAXN * sizeof(int);                    // +6.4 MB
    u16* WdT = (u16*)((char*)d_ws + off);  off += 16384 * 2;
    u16* WbT = (u16*)((char*)d_ws + off);  off += 65536 * 2;
    u16* WuT = (u16*)((char*)d_ws + off);                      // ~13.0 MB total

    const int DOWN = N / 16;                      // 3125
    const int WIN  = (E + 255) / 256;             // 6250
    const int S4   = (N * KMAXN) / 4;             // 400,000

    hipMemsetAsync(winner, 0xFF, (size_t)N * KMAXN * sizeof(int), stream);
    k_xpose<<<384, 256, 0, stream>>>(Wd, Wb, Wu, WdT, WbT, WuT);
    k_prep<<<DOWN + WIN, 256, 0, stream>>>(h, WdT, xb, eidx + E, tni, winner, E, DOWN);
    k_resolve<<<(S4 + 255) / 256, 256, 0, stream>>>(winner, eidx, S4);
    k_fused<<<DOWN, 256, 0, stream>>>(rad, xb, winner, WbT, WuT, scale, out);
}

// Round 5
// 350.259 us; speedup vs baseline: 1.1401x; 1.0400x over previous
//
#include <hip/hip_runtime.h>

typedef __attribute__((ext_vector_type(8))) short short8;
typedef __attribute__((ext_vector_type(4))) float floatx4;
typedef unsigned short u16;
typedef unsigned int u32;
typedef unsigned long long u64;

#define KMAXN 32

__device__ __forceinline__ u16 f2b(float f) {
    unsigned u = __builtin_bit_cast(unsigned, f);
    u += 0x7FFFu + ((u >> 16) & 1u);   // RNE (finite values only)
    return (u16)(u >> 16);
}
__device__ __forceinline__ float silu_f(float x) {
    return x / (1.f + __expf(-x));
}

// ---------------------------------------------------------------------------
// k_init: (a) weights f32 -> bf16 transposed; WbT2 additionally has its k-rows
// permuted to storage order i = d*16 + rbf  (orig k = rbf*64 + d) so Phase B
// can read t contiguously.  (b) zero the u64 winner table.
// ---------------------------------------------------------------------------
__global__ __launch_bounds__(256) void k_init(const float* __restrict__ Wd,
                                              const float* __restrict__ Wb,
                                              const float* __restrict__ Wu,
                                              u16* __restrict__ WdT,    // [64][256]
                                              u16* __restrict__ WbT2,   // [64][1024] permuted-k
                                              u16* __restrict__ WuT,    // [256][64]
                                              u64* __restrict__ win64,
                                              int nslots) {             // N*32
    long idx = (long)blockIdx.x * 256 + threadIdx.x;
    if (idx < 16384) {                       // WdT[n][k] = Wd[k*64+n]
        WdT[idx] = f2b(Wd[(idx & 255) * 64 + (idx >> 8)]);
    } else if (idx < 81920) {                // WbT2[n][d*16+rbf] = Wb[(rbf*64+d)*64+n]
        int i = (int)idx - 16384;
        int n = i >> 10, s = i & 1023;
        int d = s >> 4, rbf = s & 15;
        WbT2[i] = f2b(Wb[(rbf * 64 + d) * 64 + n]);
    } else if (idx < 98304) {                // WuT[n][k] = Wu[k*256+n]
        int i = (int)idx - 81920;
        WuT[i] = f2b(Wu[(i & 63) * 256 + (i >> 6)]);
    } else {
        long z = idx - 98304;                // zero winner: uint4 = 2 slots
        if (z < nslots / 2) {
            uint4 zero = {0, 0, 0, 0};
            reinterpret_cast<uint4*>(win64)[z] = zero;
        }
    }
}

// ---------------------------------------------------------------------------
// k_prep: fused down-projection (blocks [0,DOWN)) + winner scatter
// (blocks [DOWN,DOWN+WIN)).  Winner packs ((e+1)<<32)|esrc[e] into a u64
// atomicMax: max over edge id == numpy last-write-wins; low word is the
// already-resolved source atom (k_resolve eliminated).
// ---------------------------------------------------------------------------
__global__ __launch_bounds__(256) void k_prep(const float* __restrict__ h,
                                              const u16*   __restrict__ WdT,
                                              u16*         __restrict__ xb,
                                              const int*   __restrict__ esrc,
                                              const int*   __restrict__ edst,
                                              const int*   __restrict__ tni,
                                              u64*         __restrict__ win64,
                                              int E, int DOWN) {
    const int tid = threadIdx.x;
    if ((int)blockIdx.x >= DOWN) {
        int e = (blockIdx.x - DOWN) * 256 + tid;
        if (e < E) {
            u64 v = ((u64)(unsigned)(e + 1) << 32) | (u32)esrc[e];
            atomicMax(&win64[(long)edst[e] * KMAXN + tni[e]], v);
        }
        return;
    }
    // ---- down role: xb = silu(h @ Wd) as bf16, 16 atoms/block ----
    const int wave = tid >> 6;
    const int lane = tid & 63;
    const int m = lane & 15;
    const int q = lane >> 4;
    const long atom0 = (long)blockIdx.x * 16;

    const float* arow = h + (atom0 + m) * 256 + q * 8;
    const u16* brow = WdT + (wave * 16 + m) * 256 + q * 8;
    floatx4 acc = {0.f, 0.f, 0.f, 0.f};
#pragma unroll
    for (int kk = 0; kk < 8; ++kk) {
        float4 f0 = *reinterpret_cast<const float4*>(arow + kk * 32);
        float4 f1 = *reinterpret_cast<const float4*>(arow + kk * 32 + 4);
        short8 a;
        a[0] = (short)f2b(f0.x); a[1] = (short)f2b(f0.y);
        a[2] = (short)f2b(f0.z); a[3] = (short)f2b(f0.w);
        a[4] = (short)f2b(f1.x); a[5] = (short)f2b(f1.y);
        a[6] = (short)f2b(f1.z); a[7] = (short)f2b(f1.w);
        short8 b = *reinterpret_cast<const short8*>(brow + kk * 32);
        acc = __builtin_amdgcn_mfma_f32_16x16x32_bf16(a, b, acc, 0, 0, 0);
    }
#pragma unroll
    for (int r = 0; r < 4; ++r) {
        xb[(atom0 + q * 4 + r) * 64 + wave * 16 + m] = f2b(silu_f(acc[r]));
    }
}

// ---------------------------------------------------------------------------
// k_fused: einsum('nrk,nkd', rad, x2) -> @Wb*scale -> silu(@Wu)
// 256 thr = 4 waves = 16 atoms.  Phase A barrier-free (wave-private LDS).
// t stored d-major ([atom][d][rbf]) so Phase-A writes are packed b64 and
// Phase-B A-frags are contiguous b128; Wb rows pre-permuted to match.
// ---------------------------------------------------------------------------
#define T_STRIDE 1032   // t row: 1024 + 8 pad (2064 B, 16B-aligned)
#define X2_PAD   68     // x2 row: 64 + 4 pad (136 B): 4-way -> 2-way (free)

__global__ __launch_bounds__(256) void k_fused(
        const float* __restrict__ rad,     // [N][16][32] f32
        const u16*   __restrict__ xb,      // [N][64] bf16
        const u64*   __restrict__ win64,   // [N*32]: ((e+1)<<32)|src, 0 = empty
        const u16*   __restrict__ WbT2,    // [64][1024] bf16, permuted k
        const u16*   __restrict__ WuT,     // [256][64] bf16
        const float* __restrict__ scale_p, // [1]
        float* __restrict__ out) {         // [N][256] f32
    __shared__ alignas(16) u16 t2[16][T_STRIDE];       // 33.0 KB, [atom][d*16+rbf]
    __shared__ alignas(16) u16 c2_lds[16][72];         //  2.3 KB
    __shared__ alignas(16) u16 x2s[4][KMAXN][X2_PAD];  // 17.4 KB  (52.7 KB -> 3 blk/CU)

    const int tid  = threadIdx.x;
    const int wave = tid >> 6;
    const int lane = tid & 63;
    const int m = lane & 15;
    const int q = lane >> 4;
    const long atom0 = (long)blockIdx.x * 16;
    const long nbase = atom0 + wave * 4;

    // ---- Phase A ----
    const int slot = lane >> 1;
    const int half = lane & 1;

    // 1) 4 winner slots (independent loads; low word = resolved src)
    int src[4];
#pragma unroll
    for (int a = 0; a < 4; ++a) {
        u64 w = win64[(nbase + a) * KMAXN + slot];
        src[a] = w ? (int)(u32)w : -1;
    }

    // 2) 4 rad A-fragments
    short8 ra[4];
#pragma unroll
    for (int a = 0; a < 4; ++a) {
        const float* rrow = rad + (nbase + a) * 512 + m * 32 + q * 8;
        float4 r0 = *reinterpret_cast<const float4*>(rrow);
        float4 r1 = *reinterpret_cast<const float4*>(rrow + 4);
        ra[a][0] = (short)f2b(r0.x); ra[a][1] = (short)f2b(r0.y);
        ra[a][2] = (short)f2b(r0.z); ra[a][3] = (short)f2b(r0.w);
        ra[a][4] = (short)f2b(r1.x); ra[a][5] = (short)f2b(r1.y);
        ra[a][6] = (short)f2b(r1.z); ra[a][7] = (short)f2b(r1.w);
    }

    // 3) 4 gathers (lane: 32 u16 = 64 B)
    uint4 g[4][4];
#pragma unroll
    for (int a = 0; a < 4; ++a) {
        if (src[a] >= 0) {
            const uint4* p = reinterpret_cast<const uint4*>(xb + (long)src[a] * 64 + half * 32);
            g[a][0] = p[0]; g[a][1] = p[1]; g[a][2] = p[2]; g[a][3] = p[3];
        } else {
            uint4 z = {0, 0, 0, 0};
            g[a][0] = z; g[a][1] = z; g[a][2] = z; g[a][3] = z;
        }
    }

#pragma unroll
    for (int a = 0; a < 4; ++a) {
        u64* d = reinterpret_cast<u64*>(&x2s[wave][slot][half * 32]);
        const u64* s = reinterpret_cast<const u64*>(&g[a][0]);
#pragma unroll
        for (int i = 0; i < 8; ++i) d[i] = s[i];
        asm volatile("s_waitcnt lgkmcnt(0)" ::: "memory");  // drain wave's LDS writes

#pragma unroll
        for (int c = 0; c < 4; ++c) {
            short8 bx;
#pragma unroll
            for (int j = 0; j < 8; ++j) {
                bx[j] = (short)x2s[wave][q * 8 + j][c * 16 + m];
            }
            floatx4 tz = {0.f, 0.f, 0.f, 0.f};
            tz = __builtin_amdgcn_mfma_f32_16x16x32_bf16(ra[a], bx, tz, 0, 0, 0);
            // pack 4 consecutive rbf (q*4+r) of d-column c*16+m -> one b64
            u32 lo = (u32)f2b(tz[0]) | ((u32)f2b(tz[1]) << 16);
            u32 hi = (u32)f2b(tz[2]) | ((u32)f2b(tz[3]) << 16);
            u64 val = (u64)lo | ((u64)hi << 32);
            *reinterpret_cast<u64*>(&t2[wave * 4 + a][(c * 16 + m) * 16 + q * 4]) = val;
        }
        asm volatile("" ::: "memory");
    }
    __syncthreads();   // t2 crosses waves below

    // ---- Phase B: C2[16][64] = t @ Wb (both in permuted-k order), * scale ----
    floatx4 c2 = {0.f, 0.f, 0.f, 0.f};
    const u16* wbrow = WbT2 + (wave * 16 + m) * 1024 + q * 8;
#pragma unroll 4
    for (int kk = 0; kk < 32; ++kk) {
        short8 af = *reinterpret_cast<const short8*>(&t2[m][kk * 32 + q * 8]);
        short8 bf = *reinterpret_cast<const short8*>(wbrow + kk * 32);
        c2 = __builtin_amdgcn_mfma_f32_16x16x32_bf16(af, bf, c2, 0, 0, 0);
    }
    {
        float sc = scale_p[0];
#pragma unroll
        for (int r = 0; r < 4; ++r) {
            c2_lds[q * 4 + r][wave * 16 + m] = f2b(c2[r] * sc);
        }
    }
    __syncthreads();

    // ---- Phase C: out = silu(C2 @ Wu); wave w -> cols [64w, 64w+64) ----
#pragma unroll
    for (int tt = 0; tt < 4; ++tt) {
        floatx4 acc = {0.f, 0.f, 0.f, 0.f};
        const u16* wurow = WuT + (wave * 64 + tt * 16 + m) * 64 + q * 8;
#pragma unroll
        for (int ks = 0; ks < 2; ++ks) {
            short8 af = *reinterpret_cast<const short8*>(&c2_lds[m][ks * 32 + q * 8]);
            short8 bf = *reinterpret_cast<const short8*>(wurow + ks * 32);
            acc = __builtin_amdgcn_mfma_f32_16x16x32_bf16(af, bf, acc, 0, 0, 0);
        }
#pragma unroll
        for (int r = 0; r < 4; ++r) {
            out[(atom0 + q * 4 + r) * 256 + wave * 64 + tt * 16 + m] = silu_f(acc[r]);
        }
    }
}

// ---------------------------------------------------------------------------
extern "C" void kernel_launch(void* const* d_in, const int* in_sizes, int n_in,
                              void* d_out, int out_size, void* d_ws, size_t ws_size,
                              hipStream_t stream) {
    const float* h     = (const float*)d_in[0];
    const float* rad   = (const float*)d_in[1];
    const int*   eidx  = (const int*)d_in[2];   // [2][E]: row0 = src, row1 = dst
    const int*   tni   = (const int*)d_in[3];
    const float* Wd    = (const float*)d_in[4];
    const float* Wb    = (const float*)d_in[5];
    const float* Wu    = (const float*)d_in[6];
    const float* scale = (const float*)d_in[7];
    float* out         = (float*)d_out;

    const int E = in_sizes[3];            // 1,600,000
    const int N = in_sizes[0] / 256;      // 50,000
    const int nslots = N * KMAXN;

    // Workspace: xb bf16 [N*64] | win64 u64 [N*32] | WdT | WbT2 | WuT
    u16* xb = (u16*)d_ws;
    size_t off = (size_t)N * 64 * sizeof(u16);                 // 6.4 MB
    u64* win64 = (u64*)((char*)d_ws + off);
    off += (size_t)nslots * sizeof(u64);                       // +12.8 MB
    u16* WdT  = (u16*)((char*)d_ws + off);  off += 16384 * 2;
    u16* WbT2 = (u16*)((char*)d_ws + off);  off += 65536 * 2;
    u16* WuT  = (u16*)((char*)d_ws + off);                     // ~19.5 MB total

    const int DOWN = N / 16;                       // 3125
    const int WIN  = (E + 255) / 256;              // 6250
    const int INIT = 384 + (nslots / 2 + 255) / 256;

    k_init<<<INIT, 256, 0, stream>>>(Wd, Wb, Wu, WdT, WbT2, WuT, win64, nslots);
    k_prep<<<DOWN + WIN, 256, 0, stream>>>(h, WdT, xb, eidx, eidx + E, tni, win64, E, DOWN);
    k_fused<<<DOWN, 256, 0, stream>>>(rad, xb, win64, WbT2, WuT, scale, out);
}